// Round 10
// baseline (1550.327 us; speedup 1.0000x reference)
//
#include <hip/hip_runtime.h>
#include <hip/hip_bf16.h>

// Problem constants (HeteroGATLayer): H=4 heads, D=16, IN=64, E=400000, N=100000
constexpr int IN_F = 64;   // input feature dim
constexpr int HD   = 64;   // H*D

// binned sort parameters (bucketed by dst-TYPE now, not relation)
constexpr int BW_BITS = 6;
constexpr int BWIDTH  = 1 << BW_BITS;   // 64 dst nodes per bucket
constexpr int FBCAP   = 1280;           // max edges per (t,bucket), avg 768, 6sigma safe
constexpr int BIN_EPT = 16;             // edges per thread in bin pass
constexpr int BIN_CHUNK = 256 * BIN_EPT; // 4096 edges per block
constexpr int ACC_PAD  = 66;            // f32 stride of LDS accumulator rows

// MFMA projection parameters
constexpr int PROJ_ROWS  = 128;  // rows per block
constexpr int LDS_STRIDE = 72;   // bf16 elems per LDS row (also wh staging stride)
constexpr int NJOBS      = 18;   // per type: 3 ddot + 3x(4 wh + 1 sdot)

typedef __attribute__((ext_vector_type(8))) short short8;   // 8 bf16 (4 VGPRs)
typedef __attribute__((ext_vector_type(4))) float floatx4;
typedef __attribute__((ext_vector_type(8))) unsigned short us8;

static __device__ __forceinline__ float bf2f(unsigned short u) {
  union { unsigned int i; float f; } c; c.i = ((unsigned int)u) << 16; return c.f;
}
static __device__ __forceinline__ unsigned short f2bf_bits(float f) {
  union { __hip_bfloat16 h; unsigned short u; } c; c.h = __float2bfloat16(f); return c.u;
}

// ---------------------------------------------------------------------------
// Prep kernel: build MFMA B-fragment packs + bias packs. Zeroes bcnt
// (grid-stride: nbc = 3*nbuck = 4689 > 3456 threads).
// ---------------------------------------------------------------------------
struct PrepParams {
  const float* W[3][4];   // [t][p]: p0=self W_t, p1..3 = W_{t*3+(p-1)}
  const float* b[3][4];
  const float* asrc[9];
  const float* adst[9];
  unsigned short* Bpack;  // [3][18][2][64][8]
  float* biasPack;        // [3][18][16]
  unsigned* bcnt;         // zero-fill target
  int nbc;
};

__global__ __launch_bounds__(64) void prep_kernel(PrepParams pp) {
  const int t = blockIdx.x / NJOBS;
  const int j = blockIdx.x % NJOBS;
  const int lane = threadIdx.x;
  const int q = lane >> 4, n = lane & 15;

  for (int gid = blockIdx.x * 64 + lane; gid < pp.nbc; gid += 64 * gridDim.x)
    pp.bcnt[gid] = 0u;

  const float* W; const float* bv; const float* av = nullptr;
  int n0 = 0; bool dotjob;
  if (j < 3) {
    W = pp.W[t][0]; bv = pp.b[t][0]; av = pp.adst[j * 3 + t]; dotjob = true;
  } else {
    const int jj = j - 3, p = jj / 5, sub = jj % 5;
    W = pp.W[t][1 + p]; bv = pp.b[t][1 + p];
    if (sub < 4) { n0 = sub * 16; dotjob = false; }
    else { av = pp.asrc[t * 3 + p]; dotjob = true; }
  }

  unsigned short* outB = pp.Bpack + (size_t)(t * NJOBS + j) * 2 * 64 * 8;
  for (int kt = 0; kt < 2; ++kt) {
    for (int jj = 0; jj < 8; ++jj) {
      const int k = kt * 32 + q * 8 + jj;
      float v = 0.f;
      if (!dotjob) v = W[k * 64 + n0 + n];
      else if (n < 4) {
        for (int d = 0; d < 16; ++d) v += W[k * 64 + n * 16 + d] * av[n * 16 + d];
      }
      outB[(kt * 64 + lane) * 8 + jj] = f2bf_bits(v);
    }
  }
  if (lane < 16) {
    float v = 0.f;
    if (!dotjob) v = bv[n0 + lane];
    else if (lane < 4) {
      for (int d = 0; d < 16; ++d) v += bv[lane * 16 + d] * av[lane * 16 + d];
    }
    pp.biasPack[(t * NJOBS + j) * 16 + lane] = v;
  }
}

// ---------------------------------------------------------------------------
// Proj body: 4 waves x 128 rows of type t. wh staged in LDS, flushed 16B.
// ---------------------------------------------------------------------------
struct ProjParams {
  const float* feat[3];
  const unsigned short* Bpack;
  const float* biasPack;
  unsigned short* wh[9];     // out: [N, 64] bf16 bits
  float* sdot[9];            // out: [N, 4]
  float* ddot[9];            // out: [N, 4]
  int N;
};

static __device__ __forceinline__ void proj_body(const ProjParams& p, int bx, int t,
                                                 unsigned short* featL) {
  const int n0blk = bx * PROJ_ROWS;
  const int tid = threadIdx.x;
  const int N = p.N;

  {
    const float* feat = p.feat[t];
    #pragma unroll
    for (int c = 0; c < 8; ++c) {
      const int flat = c * 256 + tid;     // 0..2047 float4-slots
      const int row = flat >> 4;
      const int c4  = (flat & 15) << 2;
      const int gr = n0blk + row;
      float4 v = make_float4(0.f, 0.f, 0.f, 0.f);
      if (gr < N) v = *(const float4*)(feat + (size_t)gr * IN_F + c4);
      ushort4 o;
      o.x = f2bf_bits(v.x); o.y = f2bf_bits(v.y);
      o.z = f2bf_bits(v.z); o.w = f2bf_bits(v.w);
      *(ushort4*)(featL + row * LDS_STRIDE + c4) = o;
    }
  }
  __syncthreads();

  const int wave = tid >> 6;
  const int lane = tid & 63;
  const int q = lane >> 4, l15 = lane & 15;

  short8 afrag[2][2];
  #pragma unroll
  for (int mt = 0; mt < 2; ++mt) {
    const int row = wave * 32 + mt * 16 + l15;
    #pragma unroll
    for (int kt = 0; kt < 2; ++kt) {
      afrag[mt][kt] = *(const short8*)(featL + row * LDS_STRIDE + kt * 32 + q * 8);
    }
  }
  __syncthreads();   // featL now dead as feat buffer; reused as wh staging

  const unsigned short* Bbase = p.Bpack + (size_t)t * NJOBS * 2 * 64 * 8;
  const float* biasBase = p.biasPack + (size_t)t * NJOBS * 16;

  short8 b0 = *(const short8*)(Bbase + 0 * 512 + lane * 8);
  short8 b1 = *(const short8*)(Bbase + 1 * 512 + lane * 8);
  float bias = biasBase[l15];

  for (int j = 0; j < NJOBS; ++j) {
    short8 b0n, b1n; float biasn = 0.f;
    if (j + 1 < NJOBS) {
      b0n = *(const short8*)(Bbase + ((size_t)(j + 1) * 2 + 0) * 512 + lane * 8);
      b1n = *(const short8*)(Bbase + ((size_t)(j + 1) * 2 + 1) * 512 + lane * 8);
      biasn = biasBase[(j + 1) * 16 + l15];
    }

    #pragma unroll
    for (int mt = 0; mt < 2; ++mt) {
      floatx4 acc = {bias, bias, bias, bias};
      acc = __builtin_amdgcn_mfma_f32_16x16x32_bf16(afrag[mt][0], b0, acc, 0, 0, 0);
      acc = __builtin_amdgcn_mfma_f32_16x16x32_bf16(afrag[mt][1], b1, acc, 0, 0, 0);
      // C layout: local row = wave*32 + mt*16 + q*4 + r, col = l15
      const int lrbase = wave * 32 + mt * 16 + q * 4;
      if (j < 3) {                       // ddot job
        if (l15 < 4) {
          float* dp = p.ddot[j * 3 + t];
          #pragma unroll
          for (int r = 0; r < 4; ++r) {
            const int gr = n0blk + lrbase + r;
            if (gr < N) dp[(size_t)gr * 4 + l15] = acc[r];
          }
        }
      } else {
        const int jj = j - 3, pidx = jj / 5, sub = jj % 5, ri = t * 3 + pidx;
        if (sub < 4) {                   // wh job -> stage to LDS (bf16)
          #pragma unroll
          for (int r = 0; r < 4; ++r) {
            featL[(lrbase + r) * LDS_STRIDE + sub * 16 + l15] = f2bf_bits(acc[r]);
          }
        } else if (l15 < 4) {            // sdot job
          float* sp = p.sdot[ri];
          #pragma unroll
          for (int r = 0; r < 4; ++r) {
            const int gr = n0blk + lrbase + r;
            if (gr < N) sp[(size_t)gr * 4 + l15] = acc[r];
          }
        }
      }
    }

    // after the 4th wh sub-job of a relation: flush this wave's 32-row slab
    if (j >= 3 && ((j - 3) % 5) == 3) {
      const int ri = t * 3 + (j - 3) / 5;
      unsigned short* whp = p.wh[ri];
      const int lr = wave * 32 + (lane >> 1);      // local row (own slab)
      const int gr = n0blk + lr;
      const int c0 = (lane & 1) * 32;              // col half
      if (gr < N) {
        #pragma unroll
        for (int k2 = 0; k2 < 4; ++k2) {
          us8 v = *(const us8*)(featL + lr * LDS_STRIDE + c0 + k2 * 8);
          *(us8*)(whp + (size_t)gr * HD + c0 + k2 * 8) = v;
        }
      }
    }

    b0 = b0n; b1 = b1n; bias = biasn;
  }
}

// ---------------------------------------------------------------------------
// Bin body: buckets keyed by (dst type, dst>>6). Edge word packs
//   src (17b) | dstLow (6b) << 17 | sj (2b) << 23   (sj = src type = ri/3)
// ---------------------------------------------------------------------------
struct EdgeLists { const int* src[9]; const int* dst[9]; int E; int N; };

static __device__ __forceinline__ void bin_body(const EdgeLists& el, unsigned* bcnt,
                                                unsigned* binBuf, int nbuck,
                                                int bx, int ri, unsigned* ldsu) {
  unsigned* bh    = ldsu;
  unsigned* bcur  = ldsu + nbuck;
  unsigned* bbase = ldsu + 2 * nbuck;
  const int tid = threadIdx.x;
  const int e0  = bx * BIN_CHUNK;
  const int E   = el.E;
  const int tt  = ri % 3;      // dst type
  const int sj  = ri / 3;      // src type
  const int* srcp = el.src[ri];
  const int* dstp = el.dst[ri];

  for (int i = tid; i < nbuck; i += 256) { bh[i] = 0u; bcur[i] = 0u; }
  __syncthreads();

  int sv[BIN_EPT], dv[BIN_EPT];
  #pragma unroll
  for (int i = 0; i < BIN_EPT; ++i) {
    const int e = e0 + i * 256 + tid;
    if (e < E) {
      sv[i] = srcp[e];
      dv[i] = dstp[e];
      atomicAdd(&bh[dv[i] >> BW_BITS], 1u);
    } else dv[i] = -1;
  }
  __syncthreads();

  for (int i = tid; i < nbuck; i += 256) {
    bbase[i] = (bh[i] > 0u)
                 ? atomicAdd(bcnt + (size_t)tt * nbuck + i, bh[i]) : 0u;
  }
  __syncthreads();

  unsigned* bb = binBuf + (size_t)tt * nbuck * FBCAP;
  #pragma unroll
  for (int i = 0; i < BIN_EPT; ++i) {
    if (dv[i] >= 0) {
      const int b = dv[i] >> BW_BITS;
      const unsigned pos = bbase[b] + atomicAdd(&bcur[b], 1u);
      if (pos < (unsigned)FBCAP)
        bb[(size_t)b * FBCAP + pos] =
          (unsigned)sv[i] | ((unsigned)(dv[i] & (BWIDTH - 1)) << 17)
                          | ((unsigned)sj << 23);
    }
  }
}

// ---------------------------------------------------------------------------
// Fused kernel: proj blocks + bin blocks in one grid.
// ---------------------------------------------------------------------------
struct FusedParams {
  ProjParams proj;
  EdgeLists el;
  unsigned* bcnt;
  unsigned* binBuf;
  int nbuck;
  int projNB;   // proj x-blocks (ceil(N/PROJ_ROWS))
  int binNB;    // bin x-blocks (ceil(E/BIN_CHUNK))
};

__global__ __launch_bounds__(256) void fused_kernel(FusedParams fp) {
  __shared__ unsigned ldsU[4704];   // 18816 B: max(proj 18432, bin 3*nbuck*4)
  const int projTotal = fp.projNB * 3;
  const int bid = (int)blockIdx.x;
  if (bid < projTotal) {
    proj_body(fp.proj, bid % fp.projNB, bid / fp.projNB, (unsigned short*)ldsU);
  } else {
    const int b2 = bid - projTotal;
    bin_body(fp.el, fp.bcnt, fp.binBuf, fp.nbuck,
             b2 % fp.binNB, b2 / fp.binNB, ldsU);
  }
}

// ---------------------------------------------------------------------------
// FAB kernel: fused alpha + aggregation straight from bins.
// Block (b, t): owns dst nodes [b*64, b*64+64) of type t; iterates the
// combined 3-relation edge list; phase A computes alpha (1 thread/edge),
// phase B scatters alpha*wh into a 64x66 f32 LDS accumulator (8 thr/edge,
// ds_add_f32); output written once, coalesced. Replaces csr + agg.
// ---------------------------------------------------------------------------
struct FabParams {
  const unsigned* bcnt;      // [3][nbuck]
  const unsigned* binBuf;    // [3][nbuck][FBCAP]
  const float* sdot[9];
  const float* ddot[9];
  const unsigned short* wh[9];
  float* outp[3];
  int N, nbuck;
};

__global__ __launch_bounds__(256) void fab_kernel(FabParams fb) {
  const int t  = blockIdx.y;
  const int b  = blockIdx.x;
  const int d0 = b * BWIDTH;
  const int tid = threadIdx.x;
  const int N = fb.N;

  __shared__ float accum[BWIDTH][ACC_PAD];   // 16.9 KB
  __shared__ float ddL[3][BWIDTH][4];        // 3 KB
  __shared__ float alphaL[256][4];           // 4 KB
  __shared__ unsigned wordL[256];            // 1 KB

  for (int i = tid; i < BWIDTH * ACC_PAD; i += 256)
    (&accum[0][0])[i] = 0.f;
  if (tid < 3 * BWIDTH) {                    // stage ddot slices
    const int sj = tid >> BW_BITS, i = tid & (BWIDTH - 1);
    const int d = d0 + i;
    float4 v = make_float4(0.f, 0.f, 0.f, 0.f);
    if (d < N) v = *(const float4*)(fb.ddot[sj * 3 + t] + (size_t)d * 4);
    ddL[sj][i][0] = v.x; ddL[sj][i][1] = v.y;
    ddL[sj][i][2] = v.z; ddL[sj][i][3] = v.w;
  }
  __syncthreads();

  unsigned cnt = fb.bcnt[(size_t)t * fb.nbuck + b];
  if (cnt > (unsigned)FBCAP) cnt = FBCAP;
  const unsigned* buf = fb.binBuf + ((size_t)t * fb.nbuck + b) * FBCAP;

  const int l8 = tid & 7;          // col octet
  const int eslot = tid >> 3;      // 0..31
  const int h = l8 >> 1;           // head of this octet

  for (unsigned c0 = 0; c0 < cnt; c0 += 256) {
    const unsigned lim = (cnt - c0 < 256u) ? (cnt - c0) : 256u;

    // phase A: one thread per edge -> alpha (f32, softmax over heads)
    if (tid < (int)lim) {
      const unsigned v  = buf[c0 + tid];
      const unsigned sv = v & 0x1FFFFu;
      const unsigned dl = (v >> 17) & (BWIDTH - 1);
      const unsigned sj = v >> 23;
      const float4 sd = *(const float4*)(fb.sdot[sj * 3 + t] + (size_t)sv * 4);
      float e0 = sd.x + ddL[sj][dl][0];
      float e1 = sd.y + ddL[sj][dl][1];
      float e2 = sd.z + ddL[sj][dl][2];
      float e3 = sd.w + ddL[sj][dl][3];
      e0 = (e0 >= 0.f) ? e0 : 0.2f * e0;
      e1 = (e1 >= 0.f) ? e1 : 0.2f * e1;
      e2 = (e2 >= 0.f) ? e2 : 0.2f * e2;
      e3 = (e3 >= 0.f) ? e3 : 0.2f * e3;
      const float m = fmaxf(fmaxf(e0, e1), fmaxf(e2, e3));
      const float x0 = __expf(e0 - m);
      const float x1 = __expf(e1 - m);
      const float x2 = __expf(e2 - m);
      const float x3 = __expf(e3 - m);
      const float inv = 1.f / (x0 + x1 + x2 + x3);
      alphaL[tid][0] = x0 * inv; alphaL[tid][1] = x1 * inv;
      alphaL[tid][2] = x2 * inv; alphaL[tid][3] = x3 * inv;
      wordL[tid] = v;
    }
    __syncthreads();

    // phase B: 8 threads per edge -> gather wh row + LDS atomic accumulate
    for (unsigned j = (unsigned)eslot; j < lim; j += 32) {
      const unsigned v  = wordL[j];
      const unsigned sv = v & 0x1FFFFu;
      const unsigned dl = (v >> 17) & (BWIDTH - 1);
      const unsigned sj = v >> 23;
      const float a = alphaL[j][h];
      const us8 wv = *(const us8*)((const char*)fb.wh[sj * 3 + t]
                                   + sv * 128u + (unsigned)(l8 * 16));
      float* ar = &accum[dl][l8 * 8];
      #pragma unroll
      for (int k = 0; k < 8; ++k)
        atomicAdd(&ar[k], a * bf2f(wv[k]));
    }
    __syncthreads();
  }

  // write out: 64 rows x 64 cols, relu, coalesced float4
  float* op = fb.outp[t];
  for (int f4 = tid; f4 < BWIDTH * 16; f4 += 256) {
    const int row = f4 >> 4;
    const int c4  = (f4 & 15) << 2;
    const int d = d0 + row;
    if (d < N) {
      float4 o;
      o.x = fmaxf(accum[row][c4 + 0], 0.f);
      o.y = fmaxf(accum[row][c4 + 1], 0.f);
      o.z = fmaxf(accum[row][c4 + 2], 0.f);
      o.w = fmaxf(accum[row][c4 + 3], 0.f);
      *(float4*)(op + (size_t)d * HD + c4) = o;
    }
  }
}

// ---------------------------------------------------------------------------
extern "C" void kernel_launch(void* const* d_in, const int* in_sizes, int n_in,
                              void* d_out, int out_size, void* d_ws, size_t ws_size,
                              hipStream_t stream) {
  const int N = in_sizes[0] / IN_F;     // 100000
  const int E = in_sizes[9 + 4];        // 400000
  const int nbuck = (N + BWIDTH - 1) >> BW_BITS;  // 1563

  FusedParams fp; FabParams fb; PrepParams qq;
  ProjParams& pp = fp.proj;
  EdgeLists& el = fp.el;
  pp.N = N; el.E = E; el.N = N;
  fb.N = N; fb.nbuck = nbuck;

  for (int t = 0; t < 3; ++t) {
    pp.feat[t] = (const float*)d_in[t * 3 + 0];
    qq.W[t][0] = (const float*)d_in[t * 3 + 1];
    qq.b[t][0] = (const float*)d_in[t * 3 + 2];
    for (int j = 0; j < 3; ++j) {
      const int base = 9 + (t * 3 + j) * 6;
      qq.W[t][1 + j] = (const float*)d_in[base + 0];
      qq.b[t][1 + j] = (const float*)d_in[base + 1];
    }
  }

  // workspace carve-up
  char* ws = (char*)d_ws;
  const size_t whBytes  = (size_t)N * HD * sizeof(__hip_bfloat16); // 12.8 MB
  const size_t dotBytes = (size_t)N * 4 * sizeof(float);           // 1.6 MB
  char* whBase   = ws;                                    // 9 * 12.8 MB
  char* sdotBase = whBase + 9 * whBytes;                  // 9 * 1.6 MB
  char* ddotBase = sdotBase + 9 * dotBytes;               // 9 * 1.6 MB
  unsigned* bcnt   = (unsigned*)(ddotBase + 9 * dotBytes);         // 3*nbuck
  unsigned* binBuf = bcnt + (((size_t)3 * nbuck + 63) & ~(size_t)63);
  unsigned short* Bpack = (unsigned short*)(binBuf + (size_t)3 * nbuck * FBCAP);
  float* biasPack = (float*)(Bpack + (size_t)3 * NJOBS * 2 * 64 * 8);

  qq.Bpack = Bpack; qq.biasPack = biasPack;
  qq.bcnt = bcnt; qq.nbc = 3 * nbuck;
  pp.Bpack = Bpack; pp.biasPack = biasPack;
  fp.bcnt = bcnt; fp.binBuf = binBuf; fp.nbuck = nbuck;
  fp.projNB = (N + PROJ_ROWS - 1) / PROJ_ROWS;
  fp.binNB  = (E + BIN_CHUNK - 1) / BIN_CHUNK;
  fb.bcnt = bcnt; fb.binBuf = binBuf;

  for (int ri = 0; ri < 9; ++ri) {
    const int base = 9 + ri * 6;
    qq.asrc[ri] = (const float*)d_in[base + 2];
    qq.adst[ri] = (const float*)d_in[base + 3];
    pp.wh[ri]   = (unsigned short*)(whBase + (size_t)ri * whBytes);
    pp.sdot[ri] = (float*)(sdotBase + (size_t)ri * dotBytes);
    pp.ddot[ri] = (float*)(ddotBase + (size_t)ri * dotBytes);
    el.src[ri]  = (const int*)d_in[base + 4];
    el.dst[ri]  = (const int*)d_in[base + 5];
    fb.sdot[ri] = pp.sdot[ri];
    fb.ddot[ri] = pp.ddot[ri];
    fb.wh[ri]   = pp.wh[ri];
  }
  for (int t = 0; t < 3; ++t) fb.outp[t] = (float*)d_out + (size_t)t * N * HD;

  // ---- prep B-fragment packs + zero bcnt (must precede fused) ----
  prep_kernel<<<dim3(3 * NJOBS), 64, 0, stream>>>(qq);

  // ---- fused: MFMA projections || edge binning (independent workloads) ----
  const int nblk = fp.projNB * 3 + fp.binNB * 9;
  fused_kernel<<<dim3(nblk), 256, 0, stream>>>(fp);

  // ---- FAB: alpha + aggregation straight from bins (replaces csr + agg) ----
  fab_kernel<<<dim3(nbuck, 3), 256, 0, stream>>>(fb);
}